// Round 5
// baseline (312.793 us; speedup 1.0000x reference)
//
#include <hip/hip_runtime.h>
#include <math.h>

// Problem constants
#define B_   4096
#define T_   193
#define D_   50
#define H_   50
#define V_   11
#define BT   8                     // batch rows per block (8 of 16 MFMA cols used)
#define NBLK (B_ / BT)             // 512 blocks -> 2 blocks/CU (TLP for latency hiding)
#define CH   32                    // timesteps staged per LDS chunk
#define NCH  ((T_ + CH - 1) / CH)  // 7 chunks (6x32 + 1)

typedef __bf16 bf16x8 __attribute__((ext_vector_type(8)));
typedef float  f32x4  __attribute__((ext_vector_type(4)));

__device__ __forceinline__ float sigf(float v) { return 1.0f / (1.0f + __expf(-v)); }
__device__ __forceinline__ float thf(float v)  { return 2.0f / (1.0f + __expf(-2.0f * v)) - 1.0f; }

// Per-step GEMM  gates^T[208,16] = Wcat'[208,128] @ act^T[128,16] via
// mfma_f32_16x16x32_bf16, fp32 accum. Gate interleave g' = 4*j + q puts
// {i,f,g,o} of hidden unit j in one lane's 4 acc regs (lane-local cell update).
// K layout: [0,50) x_t; [50,64) pad; [64,114) h; [114,127) pad; 127 = bias
// (B-slot holds constant 1.0).
//
// R5 change vs R4: BT 16->8. R3/R4 showed the loop is latency-bound at
// 1 wave/SIMD (occupancy 11.7%, all pipes <50%): every barrier/LDS/trans
// latency fully exposed. 512 blocks -> 2 independent blocks per CU; one
// block's barrier stall overlaps the other's compute. LDS cut to ~72KB
// (CH=32) so two blocks fit in 160KB. Padding half the MFMA N-columns is
// free at 6% MfmaUtil.
__global__ __launch_bounds__(256, 2) void lstm_mfma_kernel(
    const float* __restrict__ x,      // [B, T, D]
    const float* __restrict__ W_ih,   // [200, 50]
    const float* __restrict__ W_hh,   // [200, 50]
    const float* __restrict__ b_ih,   // [200]
    const float* __restrict__ b_hh,   // [200]
    const float* __restrict__ fc_w,   // [11, 50]
    const float* __restrict__ fc_b,   // [11]
    float* __restrict__ out)          // [B, 11]
{
    // xs: [tc][s][lane][8 bf16] fragment-ordered x chunk. 32*2*64*16B = 64 KB
    __shared__ __align__(16) unsigned short xs[CH * 2 * 64 * 8];
    // hb: double-buffered h B-fragments + bias slot. 4 KB
    __shared__ __align__(16) unsigned short hb[2 * 2 * 64 * 8];
    __shared__ float hfin[BT * 53];
    __shared__ float lgts[BT][V_];

    const int tid  = threadIdx.x;
    const int wid  = tid >> 6;
    const int lane = tid & 63;
    const int n    = lane & 15;   // A-row within tile / B batch col
    const int kg   = lane >> 4;   // k-group
    const int row0 = blockIdx.x * BT;

    const int tbase = (wid == 0) ? 0 : (wid == 1) ? 4 : (wid == 2) ? 7 : 10;
    const int NT    = (wid == 0) ? 4 : 3;

    // ---- init hb: zeros + bias slot (u=63 -> bf16 1.0) in both buffers ----
    {
        int4 z; z.x = 0; z.y = 0; z.z = 0; z.w = 0;
        reinterpret_cast<int4*>(hb)[tid] = z;   // 256*16B = 4096B
    }
    if (tid < 32) {
        // u=63: s-half=1, frag-lane=48|n, j=7 ; bf16(1.0) = 0x3F80
        hb[((tid >> 4) * 2 + 1) * 512 + (48 + (tid & 15)) * 8 + 7] = 0x3F80;
    }

    // ---- weight A-fragments in registers (constant across t) ----
    bf16x8 wf[4][4];
    #pragma unroll
    for (int tt = 0; tt < 4; ++tt) {
        #pragma unroll
        for (int s = 0; s < 4; ++s) {
            float tv[8];
            #pragma unroll
            for (int j = 0; j < 8; ++j) tv[j] = 0.0f;
            if (tt < NT) {
                const int gp = 16 * (tbase + tt) + n;  // g'
                const int q  = gp & 3;
                const int ju = gp >> 2;
                if (ju < 50) {
                    const int row = q * 50 + ju;
                    #pragma unroll
                    for (int j = 0; j < 8; ++j) {
                        const int k = s * 32 + kg * 8 + j;
                        float v = 0.0f;
                        if (k < 50)                  v = W_ih[row * 50 + k];
                        else if (k >= 64 && k < 114) v = W_hh[row * 50 + (k - 64)];
                        else if (k == 127)           v = b_ih[row] + b_hh[row];
                        tv[j] = v;
                    }
                }
            }
            bf16x8 w;
            #pragma unroll
            for (int j = 0; j < 8; ++j) w[j] = (__bf16)tv[j];
            wf[tt][s] = w;
        }
    }

    // LDS write offsets for h (ushort index within one hb buffer)
    int hoff[4];
    #pragma unroll
    for (int tt = 0; tt < 4; ++tt) {
        const int u = 4 * (tbase + tt) + kg;
        hoff[tt] = (u >> 5) * 512 + ((((u & 31) >> 3) << 4) | n) * 8 + (u & 7);
    }

    float cst[4] = {0.0f, 0.0f, 0.0f, 0.0f};
    int cur = 0;

    for (int c = 0; c < NCH; ++c) {
        const int t0 = c * CH;
        const int L  = (T_ - t0 < CH) ? (T_ - t0) : CH;

        // ---- stage chunk: pack x[t0..t0+L) into bf16 B-fragment order ----
        const int nfrag = L * 128;
        #pragma unroll 4
        for (int fi = tid; fi < nfrag; fi += 256) {
            const int tc  = fi >> 7;
            const int rem = fi & 127;
            const int s   = rem >> 6;
            const int l   = rem & 63;
            const int nn  = l & 15;
            const int kk  = l >> 4;
            const int bn  = (nn < BT) ? nn : (BT - 1);  // pad cols re-read last row (L1 hit)
            const float* base = x + ((size_t)(row0 + bn) * T_ + (t0 + tc)) * D_;
            float2 v[4];
            #pragma unroll
            for (int j = 0; j < 4; ++j) {
                int col = 32 * s + kk * 8 + 2 * j;
                if (col > 48) col = 48;   // clamp: finite garbage * 0-weight
                v[j] = *reinterpret_cast<const float2*>(base + col);
            }
            bf16x8 w;
            #pragma unroll
            for (int j = 0; j < 4; ++j) {
                w[2 * j]     = (__bf16)v[j].x;
                w[2 * j + 1] = (__bf16)v[j].y;
            }
            reinterpret_cast<int4*>(xs)[fi] = __builtin_bit_cast(int4, w);
        }
        __syncthreads();   // one vmcnt-drain per chunk (overlapped by co-resident block)

        const int4* xsv = reinterpret_cast<const int4*>(xs);
        bf16x8 bx0 = __builtin_bit_cast(bf16x8, xsv[lane]);
        bf16x8 bx1 = __builtin_bit_cast(bf16x8, xsv[64 + lane]);

        for (int tc = 0; tc < L; ++tc) {
            const bool last = (t0 + tc == T_ - 1);

            // h fragments (written by all waves last step, visible post-barrier)
            const int4* hbv = reinterpret_cast<const int4*>(hb) + cur * 128;
            const bf16x8 bh0 = __builtin_bit_cast(bf16x8, hbv[lane]);
            const bf16x8 bh1 = __builtin_bit_cast(bf16x8, hbv[64 + lane]);

            // split accumulators: x-chain independent of the h ds_read
            f32x4 acc[4];
            #pragma unroll
            for (int tt = 0; tt < 4; ++tt) {
                if (tt < NT) {
                    f32x4 ax = {0.0f, 0.0f, 0.0f, 0.0f};
                    ax = __builtin_amdgcn_mfma_f32_16x16x32_bf16(wf[tt][0], bx0, ax, 0, 0, 0);
                    ax = __builtin_amdgcn_mfma_f32_16x16x32_bf16(wf[tt][1], bx1, ax, 0, 0, 0);
                    f32x4 ah = {0.0f, 0.0f, 0.0f, 0.0f};
                    ah = __builtin_amdgcn_mfma_f32_16x16x32_bf16(wf[tt][2], bh0, ah, 0, 0, 0);
                    ah = __builtin_amdgcn_mfma_f32_16x16x32_bf16(wf[tt][3], bh1, ah, 0, 0, 0);
                    acc[tt] = ax + ah;
                }
            }

            // prefetch next step's x frags (chunk-stable LDS; clamped at tail)
            const int tn = (tc + 1 < L) ? (tc + 1) : tc;
            const bf16x8 nx0 = __builtin_bit_cast(bf16x8, xsv[tn * 128 + lane]);
            const bf16x8 nx1 = __builtin_bit_cast(bf16x8, xsv[tn * 128 + 64 + lane]);

            // activations + h write  [gate order i,f,g,o in acc regs 0..3]
            unsigned short* hbw = hb + (cur ^ 1) * 1024;
            #pragma unroll
            for (int tt = 0; tt < 4; ++tt) {
                if (tt < NT) {
                    const float ii = sigf(acc[tt][0]);
                    const float ff = sigf(acc[tt][1]);
                    const float g2 = thf(acc[tt][2]);
                    const float oo = sigf(acc[tt][3]);
                    cst[tt] = ff * cst[tt] + ii * g2;
                    const float h = oo * thf(cst[tt]);
                    hbw[hoff[tt]] = __builtin_bit_cast(unsigned short, (__bf16)h);
                    if (last && n < BT) hfin[n * 53 + (4 * (tbase + tt) + kg)] = h;
                }
            }
            __syncthreads();   // LDS-only drain in steady state
            bx0 = nx0;
            bx1 = nx1;
            cur ^= 1;
        }
    }

    // ---- FC head + log_softmax ----
    if (tid < BT * V_) {
        const int bn = tid / V_;
        const int v  = tid % V_;
        float a = fc_b[v];
        #pragma unroll
        for (int j = 0; j < 50; ++j) {
            float hj = hfin[bn * 53 + j];
            hj = hj > 0.0f ? hj : 0.0f;
            a = fmaf(hj, fc_w[v * 50 + j], a);
        }
        lgts[bn][v] = a;
    }
    __syncthreads();
    if (tid < BT * V_) {
        const int bn = tid / V_;
        const int v  = tid % V_;
        float m = -1e30f;
        #pragma unroll
        for (int u = 0; u < V_; ++u) m = fmaxf(m, lgts[bn][u]);
        float s = 0.0f;
        #pragma unroll
        for (int u = 0; u < V_; ++u) s += __expf(lgts[bn][u] - m);
        out[(size_t)(row0 + bn) * V_ + v] = lgts[bn][v] - m - __logf(s);
    }
}

extern "C" void kernel_launch(void* const* d_in, const int* in_sizes, int n_in,
                              void* d_out, int out_size, void* d_ws, size_t ws_size,
                              hipStream_t stream) {
    const float* x    = (const float*)d_in[0];
    const float* W_ih = (const float*)d_in[1];
    const float* W_hh = (const float*)d_in[2];
    const float* b_ih = (const float*)d_in[3];
    const float* b_hh = (const float*)d_in[4];
    const float* fc_w = (const float*)d_in[5];
    const float* fc_b = (const float*)d_in[6];
    float* out = (float*)d_out;

    lstm_mfma_kernel<<<NBLK, 256, 0, stream>>>(
        x, W_ih, W_hh, b_ih, b_hh, fc_w, fc_b, out);
}

// Round 6
// 188.634 us; speedup vs baseline: 1.6582x; 1.6582x over previous
//
#include <hip/hip_runtime.h>
#include <math.h>

// Problem constants
#define B_   4096
#define T_   193
#define D_   50
#define H_   50
#define V_   11
#define BT   16                    // batch rows per block
#define NBLK (B_ / BT)             // 256 blocks = 1 block/CU (grid-limited)
#define CH   32                    // timesteps per LDS chunk (double-buffered)
#define NCH  ((T_ + CH - 1) / CH)  // 7 chunks (6x32 + 1)
#define NTHREADS 1024              // 16 waves -> 4 waves/SIMD

typedef __bf16 bf16x8 __attribute__((ext_vector_type(8)));
typedef float  f32x4  __attribute__((ext_vector_type(4)));

__device__ __forceinline__ float sigf(float v) { return 1.0f / (1.0f + __expf(-v)); }
__device__ __forceinline__ float thf(float v)  { return 2.0f / (1.0f + __expf(-2.0f * v)) - 1.0f; }

// LDS-only barrier: unlike __syncthreads (vmcnt(0) drain), this leaves global
// loads in flight -> the next-chunk x prefetch survives the 32 step barriers.
__device__ __forceinline__ void lgkm_barrier() {
    asm volatile("s_waitcnt lgkmcnt(0)\n\ts_barrier" ::: "memory");
}

// Per-step GEMM  gates^T[208,16] = Wcat'[208,128] @ act^T[128,16] via
// mfma_f32_16x16x32_bf16, fp32 accum. Gate interleave g' = 4*j + q puts
// {i,f,g,o} of hidden unit j in one lane's 4 acc regs (lane-local cell update).
// K layout: [0,50) x_t; [50,64) pad; [64,114) h; [114,127) pad; 127 = bias.
//
// R6 vs R4/R5: same total work as R4 (BT=16, 256 blocks) but 16 waves/block,
// ONE gate-tile per wave (waves 0..12 active) -> 4 waves/SIMD of independent
// dep chains to hide ds_read/trans/MFMA latency. Per-step sync is lgkm-only;
// next chunk's x is register-prefetched asynchronously across the whole
// previous chunk (HBM latency fully hidden).
__global__ __launch_bounds__(NTHREADS) void lstm_mfma_kernel(
    const float* __restrict__ x,      // [B, T, D]
    const float* __restrict__ W_ih,   // [200, 50]
    const float* __restrict__ W_hh,   // [200, 50]
    const float* __restrict__ b_ih,   // [200]
    const float* __restrict__ b_hh,   // [200]
    const float* __restrict__ fc_w,   // [11, 50]
    const float* __restrict__ fc_b,   // [11]
    float* __restrict__ out)          // [B, 11]
{
    // xs: 2 chunk buffers of [tc][s][lane][8 bf16] fragments. 2 x 64 KB
    __shared__ __align__(16) unsigned short xs[2 * CH * 2 * 64 * 8];
    // hb: double-buffered h B-fragments + bias slot. 4 KB
    __shared__ __align__(16) unsigned short hb[2 * 2 * 64 * 8];
    __shared__ float hfin[BT * 53];
    __shared__ float lgts[BT][V_];

    const int tid  = threadIdx.x;
    const int wid  = tid >> 6;
    const int lane = tid & 63;
    const int n    = lane & 15;   // A-row within tile / B batch col
    const int kg   = lane >> 4;   // k-group
    const int row0 = blockIdx.x * BT;
    const bool active = (wid < 13);
    const int  tile   = wid;      // one 16-row gate tile per wave

    // ---- init hb: zeros + bias slot (u=63 -> bf16 1.0) in both buffers ----
    if (tid < 256) {
        int4 z; z.x = 0; z.y = 0; z.z = 0; z.w = 0;
        reinterpret_cast<int4*>(hb)[tid] = z;   // 256*16B = 4096B
    }
    if (tid < 32) {
        hb[((tid >> 4) * 2 + 1) * 512 + (48 + (tid & 15)) * 8 + 7] = 0x3F80;
    }

    // ---- this wave's weight A-fragments (4 ksteps) ----
    bf16x8 wf[4];
    {
        #pragma unroll
        for (int s = 0; s < 4; ++s) {
            float tv[8];
            #pragma unroll
            for (int j = 0; j < 8; ++j) tv[j] = 0.0f;
            if (active) {
                const int gp = 16 * tile + n;  // g'
                const int q  = gp & 3;
                const int ju = gp >> 2;
                if (ju < 50) {
                    const int row = q * 50 + ju;
                    #pragma unroll
                    for (int j = 0; j < 8; ++j) {
                        const int k = s * 32 + kg * 8 + j;
                        float v = 0.0f;
                        if (k < 50)                  v = W_ih[row * 50 + k];
                        else if (k >= 64 && k < 114) v = W_hh[row * 50 + (k - 64)];
                        else if (k == 127)           v = b_ih[row] + b_hh[row];
                        tv[j] = v;
                    }
                }
            }
            bf16x8 w;
            #pragma unroll
            for (int j = 0; j < 8; ++j) w[j] = (__bf16)tv[j];
            wf[s] = w;
        }
    }

    // h LDS write offset (ushort index within one hb buffer); u = hidden unit
    const int u_   = 4 * tile + kg;
    const int hoff = (u_ >> 5) * 512 + ((((u_ & 31) >> 3) << 4) | n) * 8 + (u_ & 7);

    // ---- chunk staging: global->regs (async) then regs->LDS bf16 frags ----
    float2 P[4][4];   // 32 VGPRs; static indexing only (full unroll)

    auto loadChunk = [&](int c) {
        const int t0 = c * CH;
        const int L  = (T_ - t0 < CH) ? (T_ - t0) : CH;
        const int nfrag = L * 128;
        #pragma unroll
        for (int i = 0; i < 4; ++i) {
            const int fi = tid + i * NTHREADS;
            if (fi < nfrag) {
                const int tc  = fi >> 7;
                const int rem = fi & 127;
                const int s   = rem >> 6;
                const int l   = rem & 63;
                const int nn  = l & 15;
                const int kk  = l >> 4;
                const float* base = x + ((size_t)(row0 + nn) * T_ + (t0 + tc)) * D_;
                #pragma unroll
                for (int j = 0; j < 4; ++j) {
                    int col = 32 * s + kk * 8 + 2 * j;
                    if (col > 48) col = 48;   // clamp: finite garbage * 0-weight
                    P[i][j] = *reinterpret_cast<const float2*>(base + col);
                }
            }
        }
    };
    auto writeChunk = [&](int c, int b) {
        const int t0 = c * CH;
        const int L  = (T_ - t0 < CH) ? (T_ - t0) : CH;
        const int nfrag = L * 128;
        #pragma unroll
        for (int i = 0; i < 4; ++i) {
            const int fi = tid + i * NTHREADS;
            if (fi < nfrag) {
                bf16x8 w;
                #pragma unroll
                for (int j = 0; j < 4; ++j) {
                    w[2 * j]     = (__bf16)P[i][j].x;
                    w[2 * j + 1] = (__bf16)P[i][j].y;
                }
                reinterpret_cast<int4*>(xs)[b * (CH * 128) + fi] =
                    __builtin_bit_cast(int4, w);
            }
        }
    };

    loadChunk(0);
    writeChunk(0, 0);
    __syncthreads();        // one full (vmcnt) drain for chunk 0
    loadChunk(1);           // chunk 1 flies during chunk 0's 32 steps

    float cst = 0.0f;
    int cur = 0;
    const int4* xsv = reinterpret_cast<const int4*>(xs);

    for (int c = 0; c < NCH; ++c) {
        const int t0 = c * CH;
        const int L  = (T_ - t0 < CH) ? (T_ - t0) : CH;
        const int b  = c & 1;
        bf16x8 bx0 = __builtin_bit_cast(bf16x8, xsv[b * (CH * 128) + lane]);
        bf16x8 bx1 = __builtin_bit_cast(bf16x8, xsv[b * (CH * 128) + 64 + lane]);

        for (int tc = 0; tc < L; ++tc) {
            const bool last = (t0 + tc == T_ - 1);

            f32x4 acc;
            if (active) {
                const int4* hbv = reinterpret_cast<const int4*>(hb) + cur * 128;
                const bf16x8 bh0 = __builtin_bit_cast(bf16x8, hbv[lane]);
                const bf16x8 bh1 = __builtin_bit_cast(bf16x8, hbv[64 + lane]);
                f32x4 ax = {0.0f, 0.0f, 0.0f, 0.0f};
                ax = __builtin_amdgcn_mfma_f32_16x16x32_bf16(wf[0], bx0, ax, 0, 0, 0);
                ax = __builtin_amdgcn_mfma_f32_16x16x32_bf16(wf[1], bx1, ax, 0, 0, 0);
                f32x4 ah = {0.0f, 0.0f, 0.0f, 0.0f};
                ah = __builtin_amdgcn_mfma_f32_16x16x32_bf16(wf[2], bh0, ah, 0, 0, 0);
                ah = __builtin_amdgcn_mfma_f32_16x16x32_bf16(wf[3], bh1, ah, 0, 0, 0);
                acc = ax + ah;
            }

            // prefetch next step's x frags from chunk-stable LDS
            const int tn = (tc + 1 < L) ? (tc + 1) : tc;
            const bf16x8 nx0 = __builtin_bit_cast(
                bf16x8, xsv[b * (CH * 128) + tn * 128 + lane]);
            const bf16x8 nx1 = __builtin_bit_cast(
                bf16x8, xsv[b * (CH * 128) + tn * 128 + 64 + lane]);

            if (active) {
                const float ii = sigf(acc[0]);
                const float ff = sigf(acc[1]);
                const float g2 = thf(acc[2]);
                const float oo = sigf(acc[3]);
                cst = ff * cst + ii * g2;
                const float h = oo * thf(cst);
                hb[(cur ^ 1) * 1024 + hoff] =
                    __builtin_bit_cast(unsigned short, (__bf16)h);
                if (last) hfin[n * 53 + u_] = h;
            }

            if (tc == L - 1) {
                if (c + 1 < NCH) writeChunk(c + 1, b ^ 1);  // vmcnt waited here
                if (c + 2 < NCH) loadChunk(c + 2);          // next prefetch flies
            }

            lgkm_barrier();   // LDS-only sync; global prefetch stays in flight
            bx0 = nx0;
            bx1 = nx1;
            cur ^= 1;
        }
    }

    // ---- FC head + log_softmax ----
    if (tid < BT * V_) {
        const int bn = tid / V_;
        const int v  = tid % V_;
        float a = fc_b[v];
        #pragma unroll
        for (int j = 0; j < 50; ++j) {
            float hj = hfin[bn * 53 + j];
            hj = hj > 0.0f ? hj : 0.0f;
            a = fmaf(hj, fc_w[v * 50 + j], a);
        }
        lgts[bn][v] = a;
    }
    __syncthreads();
    if (tid < BT * V_) {
        const int bn = tid / V_;
        const int v  = tid % V_;
        float m = -1e30f;
        #pragma unroll
        for (int u = 0; u < V_; ++u) m = fmaxf(m, lgts[bn][u]);
        float s = 0.0f;
        #pragma unroll
        for (int u = 0; u < V_; ++u) s += __expf(lgts[bn][u] - m);
        out[(size_t)(row0 + bn) * V_ + v] = lgts[bn][v] - m - __logf(s);
    }
}

extern "C" void kernel_launch(void* const* d_in, const int* in_sizes, int n_in,
                              void* d_out, int out_size, void* d_ws, size_t ws_size,
                              hipStream_t stream) {
    const float* x    = (const float*)d_in[0];
    const float* W_ih = (const float*)d_in[1];
    const float* W_hh = (const float*)d_in[2];
    const float* b_ih = (const float*)d_in[3];
    const float* b_hh = (const float*)d_in[4];
    const float* fc_w = (const float*)d_in[5];
    const float* fc_b = (const float*)d_in[6];
    float* out = (float*)d_out;

    lstm_mfma_kernel<<<NBLK, NTHREADS, 0, stream>>>(
        x, W_ih, W_hh, b_ih, b_hh, fc_w, fc_b, out);
}

// Round 7
// 180.100 us; speedup vs baseline: 1.7368x; 1.0474x over previous
//
#include <hip/hip_runtime.h>
#include <math.h>

// Problem constants
#define B_   4096
#define T_   193
#define D_   50
#define H_   50
#define V_   11
#define BT   16                    // batch rows per block
#define NBLK (B_ / BT)             // 256 blocks = 1 block/CU
#define CH   32                    // timesteps per LDS chunk (double-buffered)
#define NCH  ((T_ + CH - 1) / CH)  // 7 chunks (6x32 + 1)
#define NTHREADS 832               // 13 waves, ALL active (one gate-tile each)
#define NP   ((CH * 128 + NTHREADS - 1) / NTHREADS)   // 5 staging frags/thread

typedef __bf16 bf16x8 __attribute__((ext_vector_type(8)));
typedef float  f32x4  __attribute__((ext_vector_type(4)));

__device__ __forceinline__ float sigf(float v) { return 1.0f / (1.0f + __expf(-v)); }
__device__ __forceinline__ float thf(float v)  { return 2.0f / (1.0f + __expf(-2.0f * v)) - 1.0f; }

// LDS-only barrier: leaves global loads in flight (unlike __syncthreads'
// vmcnt(0) drain) so the async next-chunk x prefetch survives step barriers.
__device__ __forceinline__ void lgkm_barrier() {
    asm volatile("s_waitcnt lgkmcnt(0)\n\ts_barrier" ::: "memory");
}

// Per-step GEMM  gates^T[208,16] = Wcat'[208,128] @ act^T[128,16] via
// mfma_f32_16x16x32_bf16, fp32 accum. Gate interleave g' = 4*j + q puts
// {i,f,g,o} of hidden unit j in one lane's 4 acc regs (lane-local cell update).
// K layout: [0,50) x_t; [50,64) pad; [64,114) h; [114,127) pad; 127 = bias.
//
// R7 vs R6: (a) 13 waves (832 thr), no idle waves; (b) the x-projection
// MFMAs for step t+1 are computed BEFORE the step-t barrier (they only need
// chunk-stable LDS) and carried as the C-operand into the post-barrier
// h-MFMA chain -> post-barrier critical path = ds_read h + 2 MFMA + act;
// (c) hfin carried in a register, written once after the loop.
__global__ __launch_bounds__(NTHREADS) void lstm_mfma_kernel(
    const float* __restrict__ x,      // [B, T, D]
    const float* __restrict__ W_ih,   // [200, 50]
    const float* __restrict__ W_hh,   // [200, 50]
    const float* __restrict__ b_ih,   // [200]
    const float* __restrict__ b_hh,   // [200]
    const float* __restrict__ fc_w,   // [11, 50]
    const float* __restrict__ fc_b,   // [11]
    float* __restrict__ out)          // [B, 11]
{
    // xs: 2 chunk buffers of [tc][s][lane][8 bf16] fragments. 2 x 64 KB
    __shared__ __align__(16) unsigned short xs[2 * CH * 2 * 64 * 8];
    // hb: double-buffered h B-fragments + bias slot. 4 KB
    __shared__ __align__(16) unsigned short hb[2 * 2 * 64 * 8];
    __shared__ float hfin[BT * 53];
    __shared__ float lgts[BT][V_];

    const int tid  = threadIdx.x;
    const int wid  = tid >> 6;
    const int lane = tid & 63;
    const int n    = lane & 15;   // A-row within tile / B batch col
    const int kg   = lane >> 4;   // k-group
    const int row0 = blockIdx.x * BT;
    const int tile = wid;         // one 16-row gate tile per wave (0..12)

    // ---- init hb: zeros + bias slot (u=63 -> bf16 1.0) in both buffers ----
    if (tid < 256) {
        int4 z; z.x = 0; z.y = 0; z.z = 0; z.w = 0;
        reinterpret_cast<int4*>(hb)[tid] = z;   // 256*16B = 4096B
    }
    if (tid < 32) {
        hb[((tid >> 4) * 2 + 1) * 512 + (48 + (tid & 15)) * 8 + 7] = 0x3F80;
    }

    // ---- this wave's weight A-fragments (4 ksteps) ----
    bf16x8 wf[4];
    {
        #pragma unroll
        for (int s = 0; s < 4; ++s) {
            float tv[8];
            #pragma unroll
            for (int j = 0; j < 8; ++j) tv[j] = 0.0f;
            const int gp = 16 * tile + n;  // g' (A-row this lane holds)
            const int q  = gp & 3;
            const int ju = gp >> 2;
            if (ju < 50) {
                const int row = q * 50 + ju;
                #pragma unroll
                for (int j = 0; j < 8; ++j) {
                    const int k = s * 32 + kg * 8 + j;
                    float v = 0.0f;
                    if (k < 50)                  v = W_ih[row * 50 + k];
                    else if (k >= 64 && k < 114) v = W_hh[row * 50 + (k - 64)];
                    else if (k == 127)           v = b_ih[row] + b_hh[row];
                    tv[j] = v;
                }
            }
            bf16x8 w;
            #pragma unroll
            for (int j = 0; j < 8; ++j) w[j] = (__bf16)tv[j];
            wf[s] = w;
        }
    }

    // h LDS write offset (ushort index within one hb buffer); u = hidden unit
    const int u_   = 4 * tile + kg;
    const int hoff = (u_ >> 5) * 512 + ((((u_ & 31) >> 3) << 4) | n) * 8 + (u_ & 7);

    // ---- chunk staging: global->regs (async) then regs->LDS bf16 frags ----
    float2 P[NP][4];   // 40 VGPRs; static indexing only (full unroll)

    auto loadChunk = [&](int c) {
        const int t0 = c * CH;
        const int L  = (T_ - t0 < CH) ? (T_ - t0) : CH;
        const int nfrag = L * 128;
        #pragma unroll
        for (int i = 0; i < NP; ++i) {
            const int fi = tid + i * NTHREADS;
            if (fi < nfrag) {
                const int tc  = fi >> 7;
                const int rem = fi & 127;
                const int s   = rem >> 6;
                const int l   = rem & 63;
                const int nn  = l & 15;
                const int kk  = l >> 4;
                const float* base = x + ((size_t)(row0 + nn) * T_ + (t0 + tc)) * D_;
                #pragma unroll
                for (int j = 0; j < 4; ++j) {
                    int col = 32 * s + kk * 8 + 2 * j;
                    if (col > 48) col = 48;   // clamp: finite garbage * 0-weight
                    P[i][j] = *reinterpret_cast<const float2*>(base + col);
                }
            }
        }
    };
    auto writeChunk = [&](int c, int b) {
        const int t0 = c * CH;
        const int L  = (T_ - t0 < CH) ? (T_ - t0) : CH;
        const int nfrag = L * 128;
        #pragma unroll
        for (int i = 0; i < NP; ++i) {
            const int fi = tid + i * NTHREADS;
            if (fi < nfrag) {
                bf16x8 w;
                #pragma unroll
                for (int j = 0; j < 4; ++j) {
                    w[2 * j]     = (__bf16)P[i][j].x;
                    w[2 * j + 1] = (__bf16)P[i][j].y;
                }
                reinterpret_cast<int4*>(xs)[b * (CH * 128) + fi] =
                    __builtin_bit_cast(int4, w);
            }
        }
    };

    loadChunk(0);
    writeChunk(0, 0);
    __syncthreads();        // one full (vmcnt) drain for chunk 0
    loadChunk(1);           // chunk 1 flies during chunk 0's 32 steps

    float cst = 0.0f;
    float hlast = 0.0f;
    int cur = 0;
    const int4* xsv = reinterpret_cast<const int4*>(xs);

    for (int c = 0; c < NCH; ++c) {
        const int t0 = c * CH;
        const int L  = (T_ - t0 < CH) ? (T_ - t0) : CH;
        const int b  = c & 1;

        // x-projection for step 0 of this chunk (buffer valid post-barrier)
        f32x4 ax;
        {
            const bf16x8 bx0 = __builtin_bit_cast(bf16x8, xsv[b * (CH * 128) + lane]);
            const bf16x8 bx1 = __builtin_bit_cast(bf16x8, xsv[b * (CH * 128) + 64 + lane]);
            f32x4 z = {0.0f, 0.0f, 0.0f, 0.0f};
            z  = __builtin_amdgcn_mfma_f32_16x16x32_bf16(wf[0], bx0, z, 0, 0, 0);
            ax = __builtin_amdgcn_mfma_f32_16x16x32_bf16(wf[1], bx1, z, 0, 0, 0);
        }

        for (int tc = 0; tc < L; ++tc) {
            // ---- post-barrier critical path: h reads -> 2 MFMA -> act ----
            const int4* hbv = reinterpret_cast<const int4*>(hb) + cur * 128;
            const bf16x8 bh0 = __builtin_bit_cast(bf16x8, hbv[lane]);
            const bf16x8 bh1 = __builtin_bit_cast(bf16x8, hbv[64 + lane]);
            f32x4 a = __builtin_amdgcn_mfma_f32_16x16x32_bf16(wf[2], bh0, ax, 0, 0, 0);
            a = __builtin_amdgcn_mfma_f32_16x16x32_bf16(wf[3], bh1, a, 0, 0, 0);

            const float ii = sigf(a[0]);
            const float ff = sigf(a[1]);
            const float g2 = thf(a[2]);
            const float oo = sigf(a[3]);
            cst = ff * cst + ii * g2;
            const float h = oo * thf(cst);
            hlast = h;
            hb[(cur ^ 1) * 1024 + hoff] =
                __builtin_bit_cast(unsigned short, (__bf16)h);

            // ---- pre-barrier slack: next step's x projection ----
            if (tc + 1 < L) {
                const bf16x8 nx0 = __builtin_bit_cast(
                    bf16x8, xsv[b * (CH * 128) + (tc + 1) * 128 + lane]);
                const bf16x8 nx1 = __builtin_bit_cast(
                    bf16x8, xsv[b * (CH * 128) + (tc + 1) * 128 + 64 + lane]);
                f32x4 z = {0.0f, 0.0f, 0.0f, 0.0f};
                z  = __builtin_amdgcn_mfma_f32_16x16x32_bf16(wf[0], nx0, z, 0, 0, 0);
                ax = __builtin_amdgcn_mfma_f32_16x16x32_bf16(wf[1], nx1, z, 0, 0, 0);
            }

            if (tc == L - 1) {
                if (c + 1 < NCH) writeChunk(c + 1, b ^ 1);  // vmcnt auto-waited
                if (c + 2 < NCH) loadChunk(c + 2);          // next prefetch flies
            }

            lgkm_barrier();   // LDS-only sync; global prefetch stays in flight
            cur ^= 1;
        }
    }

    // final h -> LDS (u_ in [0,51]; FC reads j<50)
    hfin[n * 53 + u_] = hlast;
    __syncthreads();

    // ---- FC head + log_softmax ----
    if (tid < BT * V_) {
        const int bn = tid / V_;
        const int v  = tid % V_;
        float a = fc_b[v];
        #pragma unroll
        for (int j = 0; j < 50; ++j) {
            float hj = hfin[bn * 53 + j];
            hj = hj > 0.0f ? hj : 0.0f;
            a = fmaf(hj, fc_w[v * 50 + j], a);
        }
        lgts[bn][v] = a;
    }
    __syncthreads();
    if (tid < BT * V_) {
        const int bn = tid / V_;
        const int v  = tid % V_;
        float m = -1e30f;
        #pragma unroll
        for (int u = 0; u < V_; ++u) m = fmaxf(m, lgts[bn][u]);
        float s = 0.0f;
        #pragma unroll
        for (int u = 0; u < V_; ++u) s += __expf(lgts[bn][u] - m);
        out[(size_t)(row0 + bn) * V_ + v] = lgts[bn][v] - m - __logf(s);
    }
}

extern "C" void kernel_launch(void* const* d_in, const int* in_sizes, int n_in,
                              void* d_out, int out_size, void* d_ws, size_t ws_size,
                              hipStream_t stream) {
    const float* x    = (const float*)d_in[0];
    const float* W_ih = (const float*)d_in[1];
    const float* W_hh = (const float*)d_in[2];
    const float* b_ih = (const float*)d_in[3];
    const float* b_hh = (const float*)d_in[4];
    const float* fc_w = (const float*)d_in[5];
    const float* fc_b = (const float*)d_in[6];
    float* out = (float*)d_out;

    lstm_mfma_kernel<<<NBLK, NTHREADS, 0, stream>>>(
        x, W_ih, W_hh, b_ih, b_hh, fc_w, fc_b, out);
}